// Round 8
// baseline (50.655 us; speedup 1.0000x reference)
//
#include <hip/hip_runtime.h>
#include <math.h>

#define N_CG   50000
#define APC    13
#define FEAT   128
#define DEG    16
#define VOCAB  100
#define TPAD   16              // padded row stride of T (floats) -> 64B rows
#define ZJT    16              // zj rows per table block
#define NTILE  7               // ceil(VOCAB/ZJT)
#define TBLK   (VOCAB * NTILE) // 700 table blocks
#define PACKB  ((N_CG + 255) / 256)   // 196 pack blocks
#define CG_PER_BLK 16
#define EPAD   4               // +16B row pad: rows land on distinct banks

// Kernel 1 — two independent roles:
//  blocks [0,700): T tile (zi, zj0..zj0+15). P rows recomputed in-block.
//    Fix vs R6 (which was LDS-pipe-bound at 4 FMA per ds_read + bank-aliased
//    rows): register tile (2 zj rows + zi) x 4 f per thread -> per 4-k group
//    3 ds_read_b128 + 4 float2 W-loads + 48 FMA (16:1 FMA:LDS), and +16B row
//    pad so the 2-3 distinct row addresses per wave hit distinct banks.
//  blocks [700,896): pack xyz4[i] = {x,y,z, bitcast(cg_z[i])}.
__global__ void table_pack_kernel(const float* __restrict__ emb,
                                  const float* __restrict__ Wmsg,
                                  const float* __restrict__ Wvec,
                                  const float* __restrict__ xyz,
                                  const int*   __restrict__ cg_z,
                                  float*  __restrict__ T,
                                  float4* __restrict__ xyz4) {
    int b = blockIdx.x, t = threadIdx.x;
    if (b >= TBLK) {                       // ---- pack role ----
        int i = (b - TBLK) * 256 + t;
        if (i < N_CG)
            xyz4[i] = make_float4(xyz[3*i], xyz[3*i+1], xyz[3*i+2],
                                  __int_as_float(cg_z[i]));
        return;
    }
    // ---- table role ----
    __shared__ __align__(16) float emb_lds[ZJT + 1][FEAT + EPAD];
    __shared__ float hs[ZJT][FEAT + 1];    // silu rows (padded)

    int zi    = b / NTILE;
    int zj0   = (b % NTILE) * ZJT;
    int nrows = (VOCAB - zj0 < ZJT) ? (VOCAB - zj0) : ZJT;

    // Stage 17 emb rows into LDS, coalesced (k fastest).
    for (int i = t; i < (ZJT + 1) * FEAT; i += 256) {
        int r = i >> 7, k = i & 127;
        int z = (r == ZJT) ? zi : (zj0 + r);
        if (z >= VOCAB) z = 0;             // OOB rows staged but never used
        emb_lds[r][k] = emb[z * FEAT + k];
    }
    __syncthreads();

    // Register-tiled GEMM: thread owns rows {r0, r1, zi} x f {f0,f0+1,f0+64,f0+65}
    int fq = t & 31;                       // f-quad id (lanes 0..31 coalesced)
    int rg = t >> 5;                       // row-group 0..7
    int f0 = fq * 2;
    int r0 = rg * 2, r1 = r0 + 1;

    float accA[4] = {0.f, 0.f, 0.f, 0.f};  // row r0
    float accB[4] = {0.f, 0.f, 0.f, 0.f};  // row r1
    float accZ[4] = {0.f, 0.f, 0.f, 0.f};  // row zi

    for (int k0 = 0; k0 < FEAT; k0 += 4) {
        float4 eA = *(const float4*)&emb_lds[r0][k0];
        float4 eB = *(const float4*)&emb_lds[r1][k0];
        float4 eZ = *(const float4*)&emb_lds[ZJT][k0];
        float ea[4] = {eA.x, eA.y, eA.z, eA.w};
        float eb[4] = {eB.x, eB.y, eB.z, eB.w};
        float ez[4] = {eZ.x, eZ.y, eZ.z, eZ.w};
        #pragma unroll
        for (int kk = 0; kk < 4; ++kk) {
            float2 wa = *(const float2*)&Wmsg[(k0 + kk) * FEAT + f0];
            float2 wb = *(const float2*)&Wmsg[(k0 + kk) * FEAT + f0 + 64];
            accA[0] += ea[kk] * wa.x;  accA[1] += ea[kk] * wa.y;
            accA[2] += ea[kk] * wb.x;  accA[3] += ea[kk] * wb.y;
            accB[0] += eb[kk] * wa.x;  accB[1] += eb[kk] * wa.y;
            accB[2] += eb[kk] * wb.x;  accB[3] += eb[kk] * wb.y;
            accZ[0] += ez[kk] * wa.x;  accZ[1] += ez[kk] * wa.y;
            accZ[2] += ez[kk] * wb.x;  accZ[3] += ez[kk] * wb.y;
        }
    }

    // zero-rule (S_I[z]=0 for z==0), silu, write hs rows (2-way write conflict = free).
    int zjA = zj0 + r0, zjB = zj0 + r1;
    bool vA = (zjA != 0 && zjA < VOCAB);
    bool vB = (zjB != 0 && zjB < VOCAB);
    #pragma unroll
    for (int j = 0; j < 4; ++j) {
        int f = (j < 2) ? (f0 + j) : (f0 + 62 + j);   // f0,f0+1,f0+64,f0+65
        float pz = (zi != 0) ? accZ[j] : 0.f;
        float hA = pz + (vA ? accA[j] : 0.f);
        float hB = pz + (vB ? accB[j] : 0.f);
        hs[r0][f] = hA / (1.f + expf(-hA));
        hs[r1][f] = hB / (1.f + expf(-hB));
    }
    __syncthreads();

    if (t < nrows * APC) {                 // phase B (R1's proven structure)
        int r = t / APC, c = t % APC;
        float s = 0.f;
        #pragma unroll 8
        for (int ff = 0; ff < FEAT; ++ff)
            s += hs[r][ff] * Wvec[ff * APC + c];     // Wvec 6.5KB, L1-resident
        T[(size_t)(zi * VOCAB + zj0 + r) * TPAD + c] = s;
    }
}

// Kernel 2 — fused segment-sum + reconstruction (unchanged from R6).
__global__ void recon_kernel(const float4* __restrict__ xyz4,
                             const int*    __restrict__ nbr,
                             const int*    __restrict__ ca_idx,
                             const float*  __restrict__ T,
                             float* __restrict__ out) {
    __shared__ float4 eu[CG_PER_BLK][DEG + 1];     // padded: conflict-free
    __shared__ float4 xis[CG_PER_BLK];
    __shared__ float  obuf[CG_PER_BLK * APC * 3];  // 624 floats

    int t = threadIdx.x;
    int cg0 = blockIdx.x * CG_PER_BLK;

    {   // phase 1: one edge per thread
        int g = t >> 4, k = t & 15;
        int cg = cg0 + g;
        int e  = cg * DEG + k;             // src = repeat(arange(N_CG), DEG)
        int2 ed = ((const int2*)nbr)[e];   // {src, dst} in one 8B load
        int j = ed.y;
        float4 pj = xyz4[j];
        float4 pi = xyz4[cg];
        if (k == 0) xis[g] = pi;
        float dx = pj.x - pi.x, dy = pj.y - pi.y, dz = pj.z - pi.z;
        float inv = 1.f / (sqrtf(dx*dx + dy*dy + dz*dz) + 1e-8f);
        int row = __float_as_int(pi.w) * VOCAB + __float_as_int(pj.w);
        eu[g][k] = make_float4(dx*inv, dy*inv, dz*inv, __int_as_float(row));
    }
    __syncthreads();

    if (t < CG_PER_BLK * APC) {            // phase 2
        int g = t / APC, c = t % APC;
        int cg = cg0 + g;
        float a0 = 0.f, a1 = 0.f, a2 = 0.f;
        #pragma unroll
        for (int k = 0; k < DEG; ++k) {
            float4 u = eu[g][k];
            int row = __float_as_int(u.w);
            float w = T[(size_t)row * TPAD + c];
            a0 += w * u.x; a1 += w * u.y; a2 += w * u.z;
        }
        // ca atom: channel = ca_idx[cg] - first, first = cg*APC
        if (c == ca_idx[cg] - cg * APC) { a0 = 0.f; a1 = 0.f; a2 = 0.f; }
        float4 xi = xis[g];
        obuf[t * 3 + 0] = a0 + xi.x;
        obuf[t * 3 + 1] = a1 + xi.y;
        obuf[t * 3 + 2] = a2 + xi.z;
    }
    __syncthreads();

    if (t < (CG_PER_BLK * APC * 3) / 4) {  // 156 float4, contiguous 2496B
        float4* ov = (float4*)(out + (size_t)blockIdx.x * (CG_PER_BLK * APC * 3));
        ov[t] = ((const float4*)obuf)[t];
    }
}

extern "C" void kernel_launch(void* const* d_in, const int* in_sizes, int n_in,
                              void* d_out, int out_size, void* d_ws, size_t ws_size,
                              hipStream_t stream) {
    const float* cg_xyz  = (const float*)d_in[0];
    const float* emb     = (const float*)d_in[1];
    const float* W_msg   = (const float*)d_in[2];
    const float* W_vec   = (const float*)d_in[3];
    const int*   cg_z    = (const int*)d_in[4];
    const int*   nbr     = (const int*)d_in[5];
    const int*   ca_idx  = (const int*)d_in[7];
    float* out = (float*)d_out;

    float*  T    = (float*)d_ws;                                   // 640 KB
    float4* xyz4 = (float4*)((char*)d_ws + (size_t)VOCAB*VOCAB*TPAD*4);

    table_pack_kernel<<<TBLK + PACKB, 256, 0, stream>>>(
        emb, W_msg, W_vec, cg_xyz, cg_z, T, xyz4);
    recon_kernel<<<N_CG / CG_PER_BLK, 256, 0, stream>>>(
        xyz4, nbr, ca_idx, T, out);
}

// Round 9
// 31.667 us; speedup vs baseline: 1.5996x; 1.5996x over previous
//
#include <hip/hip_runtime.h>
#include <math.h>

#define N_CG   50000
#define APC    13
#define FEAT   128
#define DEG    16
#define VOCAB  100
#define TPAD   16              // padded row stride of T (floats) -> 64B rows
#define ROWS_PER_BLK 16        // table: rows per block
#define CG_PER_BLK 16          // recon: cgs per block
#define PBLK   (VOCAB / 2)     // 50 GEMM blocks (2 z-rows per 256-thread block)
#define PACKB  ((N_CG + 255) / 256)

// Kernel 1 (R3-exact): role A (blocks [0,50)): P = (z!=0 ? emb[z]:0) @ W_msg.
//                      role B (blocks [50,246)): xyz4[i]={x,y,z,bitcast(cg_z)}.
__global__ void p_pack_kernel(const float* __restrict__ emb,
                              const float* __restrict__ Wmsg,
                              const float* __restrict__ xyz,
                              const int*   __restrict__ cg_z,
                              float*  __restrict__ P,
                              float4* __restrict__ xyz4) {
    int b = blockIdx.x, t = threadIdx.x;
    if (b < PBLK) {                        // role A: P GEMM (once, 1.6M MAC)
        int z = b * 2 + (t >> 7);          // wave-uniform z
        int f = t & 127;
        float acc = 0.f;
        if (z != 0) {
            #pragma unroll 8
            for (int k = 0; k < FEAT; ++k)
                acc += emb[z * FEAT + k] * Wmsg[k * FEAT + f];
        }
        P[z * FEAT + f] = acc;
        return;
    }
    int i = (b - PBLK) * 256 + t;          // role B: pack
    if (i < N_CG)
        xyz4[i] = make_float4(xyz[3*i], xyz[3*i+1], xyz[3*i+2],
                              __int_as_float(cg_z[i]));
}

// Kernel 2 (R3-exact): T[row][c] = silu(P[zi]+P[zj]) @ W_vec, stride TPAD.
__global__ void table_kernel(const float* __restrict__ P,
                             const float* __restrict__ Wvec,
                             float* __restrict__ T) {
    __shared__ float hs[ROWS_PER_BLK][FEAT + 1];
    int t = threadIdx.x;
    int row0 = blockIdx.x * ROWS_PER_BLK;
    #pragma unroll
    for (int i = 0; i < (ROWS_PER_BLK * FEAT) / 256; ++i) {
        int v = t + i * 256;
        int r = v >> 7, f = v & 127;
        int row = row0 + r;
        int zi = row / VOCAB, zj = row % VOCAB;
        float h = P[zi * FEAT + f] + P[zj * FEAT + f];
        hs[r][f] = h / (1.f + expf(-h));   // silu
    }
    __syncthreads();
    if (t < ROWS_PER_BLK * APC) {
        int r = t / APC, c = t % APC;
        float s = 0.f;
        #pragma unroll 8
        for (int f = 0; f < FEAT; ++f)
            s += hs[r][f] * Wvec[f * APC + c];
        T[(size_t)(row0 + r) * TPAD + c] = s;
    }
}

// Kernel 3: recon with batched phase-2 ILP.
// Phase 1: 256 edges/block, one int2 + two float4 gathers each; ca_idx staged.
// Phase 2: (cg,channel) threads: ALL 16 LDS records -> registers, then ALL 16
//   independent T-gathers issued (vmcnt-batched), then FMA reduction.
__global__ void recon_kernel(const float4* __restrict__ xyz4,
                             const int*    __restrict__ nbr,
                             const int*    __restrict__ ca_idx,
                             const float*  __restrict__ T,
                             float* __restrict__ out) {
    __shared__ float4 eu[CG_PER_BLK][DEG + 1];     // padded: conflict-free
    __shared__ float4 xis[CG_PER_BLK];
    __shared__ int    cas[CG_PER_BLK];
    __shared__ float  obuf[CG_PER_BLK * APC * 3];  // 624 floats

    int t = threadIdx.x;
    int cg0 = blockIdx.x * CG_PER_BLK;

    {   // phase 1: one edge per thread
        int g = t >> 4, k = t & 15;
        int cg = cg0 + g;
        int e  = cg * DEG + k;             // src = repeat(arange(N_CG), DEG)
        int2 ed = ((const int2*)nbr)[e];   // {src, dst} one 8B load
        int j = ed.y;
        float4 pj = xyz4[j];
        float4 pi = xyz4[cg];
        if (k == 0) xis[g] = pi;
        if (k == 1) cas[g] = ca_idx[cg];
        float dx = pj.x - pi.x, dy = pj.y - pi.y, dz = pj.z - pi.z;
        float inv = 1.f / (sqrtf(dx*dx + dy*dy + dz*dz) + 1e-8f);
        int row = __float_as_int(pi.w) * VOCAB + __float_as_int(pj.w);
        eu[g][k] = make_float4(dx*inv, dy*inv, dz*inv, __int_as_float(row));
    }
    __syncthreads();

    if (t < CG_PER_BLK * APC) {            // phase 2
        int g = t / APC, c = t % APC;
        float4 u[DEG];
        #pragma unroll
        for (int k = 0; k < DEG; ++k) u[k] = eu[g][k];   // LDS -> regs, batched
        float w[DEG];
        #pragma unroll
        for (int k = 0; k < DEG; ++k)                    // 16 independent gathers
            w[k] = T[(size_t)__float_as_int(u[k].w) * TPAD + c];
        float a0 = 0.f, a1 = 0.f, a2 = 0.f;
        #pragma unroll
        for (int k = 0; k < DEG; ++k) {
            a0 += w[k] * u[k].x; a1 += w[k] * u[k].y; a2 += w[k] * u[k].z;
        }
        int cg = cg0 + g;
        if (c == cas[g] - cg * APC) { a0 = 0.f; a1 = 0.f; a2 = 0.f; }  // ca atom
        float4 xi = xis[g];
        obuf[t * 3 + 0] = a0 + xi.x;
        obuf[t * 3 + 1] = a1 + xi.y;
        obuf[t * 3 + 2] = a2 + xi.z;
    }
    __syncthreads();

    if (t < (CG_PER_BLK * APC * 3) / 4) {  // 156 float4, contiguous 2496B
        float4* ov = (float4*)(out + (size_t)blockIdx.x * (CG_PER_BLK * APC * 3));
        ov[t] = ((const float4*)obuf)[t];
    }
}

extern "C" void kernel_launch(void* const* d_in, const int* in_sizes, int n_in,
                              void* d_out, int out_size, void* d_ws, size_t ws_size,
                              hipStream_t stream) {
    const float* cg_xyz  = (const float*)d_in[0];
    const float* emb     = (const float*)d_in[1];
    const float* W_msg   = (const float*)d_in[2];
    const float* W_vec   = (const float*)d_in[3];
    const int*   cg_z    = (const int*)d_in[4];
    const int*   nbr     = (const int*)d_in[5];
    const int*   ca_idx  = (const int*)d_in[7];
    float* out = (float*)d_out;

    float*  T    = (float*)d_ws;                                        // 640 KB
    float4* xyz4 = (float4*)((char*)d_ws + (size_t)VOCAB*VOCAB*TPAD*4); // 800 KB
    float*  P    = (float*)((char*)xyz4 + (size_t)N_CG * 16);           // 51.2 KB

    p_pack_kernel<<<PBLK + PACKB, 256, 0, stream>>>(
        emb, W_msg, cg_xyz, cg_z, P, xyz4);
    table_kernel<<<(VOCAB * VOCAB) / ROWS_PER_BLK, 256, 0, stream>>>(
        P, W_vec, T);
    recon_kernel<<<N_CG / CG_PER_BLK, 256, 0, stream>>>(
        xyz4, nbr, ca_idx, T, out);
}